// Round 1
// baseline (588.838 us; speedup 1.0000x reference)
//
#include <hip/hip_runtime.h>
#include <hip/hip_bf16.h>

#define T_DIM   2048
#define B_DIM   64
#define IN_DIM  256
#define H_DIM   256
#define M_TOT   (T_DIM * B_DIM)              // 131072
#define LAST_ROW0 (M_TOT - B_DIM)            // 131008
#define OUT_MAIN ((size_t)M_TOT * H_DIM)     // 33554432

#define BM  128
#define LDK 264   // padded bf16 K-stride (+8) to break LDS bank aliasing

typedef __bf16 bf16x8 __attribute__((ext_vector_type(8)));
typedef float  floatx4 __attribute__((ext_vector_type(4)));

__device__ __forceinline__ unsigned short f2bf(float f) {
    // RNE fp32 -> bf16 (inputs are finite; no NaN handling needed)
    unsigned int u = __float_as_uint(f);
    unsigned int r = u + 0x7FFFu + ((u >> 16) & 1u);
    return (unsigned short)(r >> 16);
}

__device__ __forceinline__ float sigf(float v) {
    return 1.0f / (1.0f + __expf(-v));
}

// ---------------------------------------------------------------------------
// Prep: ghpack[b][h] = {gh_r + b_ih_r, gh_z + b_ih_z, gh_n, hid[b][h]}
//       wsB = w_ih as bf16, swizzled into MFMA 16x16x32 B-fragment order
//       biasn[h] = b_ih[2H + h]
// ---------------------------------------------------------------------------
__global__ void __launch_bounds__(256) gru_prep(
    const float* __restrict__ hid, const float* __restrict__ w_ih,
    const float* __restrict__ w_hh, const float* __restrict__ b_ih,
    const float* __restrict__ b_hh, unsigned short* __restrict__ wsB,
    float4* __restrict__ ghpack, float* __restrict__ biasn)
{
    const int blk = blockIdx.x, tid = threadIdx.x;
    if (blk < 64) {
        const int bb = blk, h = tid;
        const float4* hv4 = (const float4*)(hid + (size_t)bb * H_DIM);
        const float4* w0  = (const float4*)(w_hh + (size_t)h * H_DIM);
        const float4* w1  = (const float4*)(w_hh + (size_t)(H_DIM + h) * H_DIM);
        const float4* w2  = (const float4*)(w_hh + (size_t)(2 * H_DIM + h) * H_DIM);
        float s0 = 0.f, s1 = 0.f, s2 = 0.f;
        for (int k = 0; k < H_DIM / 4; k++) {
            float4 hv = hv4[k];
            float4 a = w0[k]; s0 += hv.x*a.x + hv.y*a.y + hv.z*a.z + hv.w*a.w;
            float4 b = w1[k]; s1 += hv.x*b.x + hv.y*b.y + hv.z*b.z + hv.w*b.w;
            float4 c = w2[k]; s2 += hv.x*c.x + hv.y*c.y + hv.z*c.z + hv.w*c.w;
        }
        float4 o;
        o.x = s0 + b_hh[h]             + b_ih[h];
        o.y = s1 + b_hh[H_DIM + h]     + b_ih[H_DIM + h];
        o.z = s2 + b_hh[2 * H_DIM + h];                    // i_n bias kept separate
        o.w = hid[(size_t)bb * H_DIM + h];
        ghpack[bb * H_DIM + h] = o;
    } else if (blk < 160) {
        // fragment entry idx: ((ntile*8 + kstep)*64 + lane), 8 bf16 each
        const int idx   = (blk - 64) * 256 + tid;   // 0..24575
        const int lane  = idx & 63;
        const int kstep = (idx >> 6) & 7;
        const int ntile = idx >> 9;                 // 0..47 over N=768
        const int n = ntile * 16 + (lane & 15);
        const int k = kstep * 32 + (lane >> 4) * 8;
        const float* src = w_ih + (size_t)n * IN_DIM + k;
        unsigned short* dst = wsB + (size_t)idx * 8;
        #pragma unroll
        for (int j = 0; j < 8; j++) dst[j] = f2bf(src[j]);
    } else {
        biasn[tid] = b_ih[2 * H_DIM + tid];
    }
}

// ---------------------------------------------------------------------------
// Main: fused GEMM (x bf16 @ w_ih^T) + GRU epilogue
// grid 1024, block 512 (8 waves: 2 M-split x 4 N-split)
// ---------------------------------------------------------------------------
__global__ void __launch_bounds__(512, 4) gru_main(
    const float* __restrict__ x, const unsigned short* __restrict__ wsB,
    const float4* __restrict__ ghpack, const float* __restrict__ biasn,
    float* __restrict__ out)
{
    __shared__ unsigned short As[BM * LDK];   // 128 x 264 bf16 = 67584 B
    const int tid = threadIdx.x;
    const int m0  = blockIdx.x * BM;

    // ---- stage A tile: 128 rows x 256 K, fp32 -> bf16, coalesced float4 loads
    {
        const float4* xt = (const float4*)(x + (size_t)m0 * IN_DIM);
        #pragma unroll
        for (int i = 0; i < 16; i++) {
            const int f  = tid + i * 512;   // 0..8191 float4s
            const int r  = f >> 6;          // 64 float4 per row
            const int c4 = f & 63;
            float4 v = xt[f];
            ushort4 s;
            s.x = f2bf(v.x); s.y = f2bf(v.y); s.z = f2bf(v.z); s.w = f2bf(v.w);
            *reinterpret_cast<ushort4*>(&As[r * LDK + (c4 << 2)]) = s;
        }
    }
    __syncthreads();

    const int lane  = tid & 63;
    const int wid   = tid >> 6;
    const int waveM = wid & 1;    // 2-way M split (64 rows each)
    const int waveN = wid >> 1;   // 4-way N split (16 cols each of 64-col chunk)
    const int lr = lane & 15;
    const int lq = lane >> 4;

    #pragma unroll 1
    for (int ho = 0; ho < 4; ho++) {
        floatx4 acc[3][4];
        #pragma unroll
        for (int g = 0; g < 3; g++)
            #pragma unroll
            for (int rf = 0; rf < 4; rf++)
                acc[g][rf] = (floatx4){0.f, 0.f, 0.f, 0.f};

        #pragma unroll
        for (int ks = 0; ks < 8; ks++) {
            bf16x8 a[4];
            #pragma unroll
            for (int rf = 0; rf < 4; rf++)
                a[rf] = *reinterpret_cast<const bf16x8*>(
                    &As[(waveM * 64 + rf * 16 + lr) * LDK + ks * 32 + lq * 8]);
            #pragma unroll
            for (int g = 0; g < 3; g++) {
                const int ntile = g * 16 + ho * 4 + waveN;
                const bf16x8 bfrag = *reinterpret_cast<const bf16x8*>(
                    wsB + (((size_t)ntile * 8 + ks) * 64 + lane) * 8);
                #pragma unroll
                for (int rf = 0; rf < 4; rf++)
                    acc[g][rf] = __builtin_amdgcn_mfma_f32_16x16x32_bf16(
                        a[rf], bfrag, acc[g][rf], 0, 0, 0);
            }
        }

        // ---- epilogue: C/D layout col = lane&15, row = lq*4 + reg
        const int h  = ho * 64 + waveN * 16 + lr;
        const float bn = biasn[h];
        #pragma unroll
        for (int rf = 0; rf < 4; rf++) {
            const int mb = m0 + waveM * 64 + rf * 16 + lq * 4;
            const int b0 = mb & 63;
            #pragma unroll
            for (int reg = 0; reg < 4; reg++) {
                const float4 gp = ghpack[(b0 + reg) * H_DIM + h];
                const float r = sigf(acc[0][rf][reg] + gp.x);
                const float z = sigf(acc[1][rf][reg] + gp.y);
                const float e = __expf(-2.0f * (acc[2][rf][reg] + bn + r * gp.z));
                const float n = (1.0f - e) / (1.0f + e);
                const float o = (1.0f - z) * n + z * gp.w;
                const int m = mb + reg;
                out[(size_t)m * H_DIM + h] = o;
                if (m >= LAST_ROW0)
                    out[OUT_MAIN + (size_t)(m - LAST_ROW0) * H_DIM + h] = o;
            }
        }
    }
}

extern "C" void kernel_launch(void* const* d_in, const int* in_sizes, int n_in,
                              void* d_out, int out_size, void* d_ws, size_t ws_size,
                              hipStream_t stream) {
    const float* x    = (const float*)d_in[0];
    const float* hid  = (const float*)d_in[1];
    const float* w_ih = (const float*)d_in[2];
    const float* w_hh = (const float*)d_in[3];
    const float* b_ih = (const float*)d_in[4];
    const float* b_hh = (const float*)d_in[5];
    float* out = (float*)d_out;

    char* ws = (char*)d_ws;
    unsigned short* wsB = (unsigned short*)ws;              // 768*256*2 = 393216 B
    float4* ghpack = (float4*)(ws + 393216);                // 64*256*16 = 262144 B
    float*  biasn  = (float*)(ws + 393216 + 262144);        // 1024 B

    gru_prep<<<161, 256, 0, stream>>>(hid, w_ih, w_hh, b_ih, b_hh, wsB, ghpack, biasn);
    gru_main<<<1024, 512, 0, stream>>>(x, wsB, ghpack, biasn, out);
}

// Round 2
// 314.295 us; speedup vs baseline: 1.8735x; 1.8735x over previous
//
#include <hip/hip_runtime.h>
#include <hip/hip_bf16.h>

#define T_DIM   2048
#define B_DIM   64
#define IN_DIM  256
#define H_DIM   256
#define M_TOT   (T_DIM * B_DIM)              // 131072
#define LAST_ROW0 (M_TOT - B_DIM)            // 131008
#define OUT_MAIN ((size_t)M_TOT * H_DIM)     // 33554432

typedef __bf16 bf16x8 __attribute__((ext_vector_type(8)));
typedef float  floatx4 __attribute__((ext_vector_type(4)));

__device__ __forceinline__ unsigned short f2bf(float f) {
    unsigned int u = __float_as_uint(f);
    unsigned int r = u + 0x7FFFu + ((u >> 16) & 1u);
    return (unsigned short)(r >> 16);
}
__device__ __forceinline__ float sigf(float v) {
    return 1.0f / (1.0f + __expf(-v));
}

// ---------------------------------------------------------------------------
// Prep: ghpack[b][h] = {gh_r + b_ih_r, gh_z + b_ih_z, gh_n, hid[b][h]}
//       wsA = w_ih bf16 swizzled into MFMA 16x16x32 A-fragment order
//             (lane&15 -> row n, (lane>>4)*8+j -> k), entry idx
//             ((ntile*8 + kstep)*64 + lane)*8
//       biasn[h] = b_ih[2H + h]
// ---------------------------------------------------------------------------
__global__ void __launch_bounds__(256) gru_prep(
    const float* __restrict__ hid, const float* __restrict__ w_ih,
    const float* __restrict__ w_hh, const float* __restrict__ b_ih,
    const float* __restrict__ b_hh, unsigned short* __restrict__ wsA,
    float4* __restrict__ ghpack, float* __restrict__ biasn)
{
    const int blk = blockIdx.x, tid = threadIdx.x;
    if (blk < 64) {
        const int bb = blk, h = tid;
        const float4* hv4 = (const float4*)(hid + (size_t)bb * H_DIM);
        const float4* w0  = (const float4*)(w_hh + (size_t)h * H_DIM);
        const float4* w1  = (const float4*)(w_hh + (size_t)(H_DIM + h) * H_DIM);
        const float4* w2  = (const float4*)(w_hh + (size_t)(2 * H_DIM + h) * H_DIM);
        float s0 = 0.f, s1 = 0.f, s2 = 0.f;
        for (int k = 0; k < H_DIM / 4; k++) {
            float4 hv = hv4[k];
            float4 a = w0[k]; s0 += hv.x*a.x + hv.y*a.y + hv.z*a.z + hv.w*a.w;
            float4 b = w1[k]; s1 += hv.x*b.x + hv.y*b.y + hv.z*b.z + hv.w*b.w;
            float4 c = w2[k]; s2 += hv.x*c.x + hv.y*c.y + hv.z*c.z + hv.w*c.w;
        }
        float4 o;
        o.x = s0 + b_hh[h]             + b_ih[h];
        o.y = s1 + b_hh[H_DIM + h]     + b_ih[H_DIM + h];
        o.z = s2 + b_hh[2 * H_DIM + h];
        o.w = hid[(size_t)bb * H_DIM + h];
        ghpack[bb * H_DIM + h] = o;
    } else if (blk < 160) {
        const int idx   = (blk - 64) * 256 + tid;   // 0..24575
        const int lane  = idx & 63;
        const int kstep = (idx >> 6) & 7;
        const int ntile = idx >> 9;                 // 0..47 over N=768
        const int n = ntile * 16 + (lane & 15);
        const int k = kstep * 32 + (lane >> 4) * 8;
        const float* src = w_ih + (size_t)n * IN_DIM + k;
        unsigned short* dst = wsA + (size_t)idx * 8;
        #pragma unroll
        for (int j = 0; j < 8; j++) dst[j] = f2bf(src[j]);
    } else {
        biasn[tid] = b_ih[2 * H_DIM + tid];
    }
}

// ---------------------------------------------------------------------------
// Main (transposed MFMA): A = w_ih (regs, fixed), B = x tile (LDS, dbuf).
// Block: 512 thr = 8 waves; wave owns 16 h of its h-half. Block owns bq
// (b-quarter) and 16 consecutive t. C/D: col=lane&15 -> m, row -> h.
// ---------------------------------------------------------------------------
#define LDXB 264   // bf16 row stride for x tile (256 + 8 pad)

__global__ void __launch_bounds__(512, 2) gru_main(
    const float* __restrict__ x, const unsigned short* __restrict__ wsA,
    const float4* __restrict__ ghpack, const float* __restrict__ biasn,
    float* __restrict__ out)
{
    __shared__ unsigned short xsb[2][16 * LDXB];   // 2 x 8448 B
    __shared__ float epi[8][16 * 20];              // 10240 B, per-wave private

    const int tid  = threadIdx.x;
    const int lane = tid & 63;
    const int wid  = tid >> 6;
    const int lr = lane & 15, lq = lane >> 4;

    // XCD-pair swizzle: raw and raw^8 (the two h-halves of the same (bq,tc))
    // land on the same XCD under round-robin dispatch -> shared x lines in L2.
    const int raw  = blockIdx.x;
    const int half = (raw >> 3) & 1;
    const int p    = (raw & 7) | ((raw >> 4) << 3);   // 0..511
    const int bq   = p & 3;
    const int tc   = p >> 2;                          // 0..127, 16 t each
    const int hbase = half * 128 + wid * 16;

    // ---- A fragments: w_ih for 3 gates x K=256, fixed for whole block
    bf16x8 afrag[3][8];
    #pragma unroll
    for (int g = 0; g < 3; g++) {
        const int ntile = g * 16 + half * 8 + wid;
        #pragma unroll
        for (int ks = 0; ks < 8; ks++)
            afrag[g][ks] = *reinterpret_cast<const bf16x8*>(
                wsA + (((size_t)ntile * 8 + ks) * 64 + lane) * 8);
    }
    // ---- per-(b,h) GRU state, fixed for whole block: b = bq*16+lr
    float4 gp[4]; float bn[4];
    #pragma unroll
    for (int reg = 0; reg < 4; reg++) {
        gp[reg] = ghpack[(bq * 16 + lr) * H_DIM + hbase + lq * 4 + reg];
        bn[reg] = biasn[hbase + lq * 4 + reg];
    }

    const float4* xt = (const float4*)x;
    const int f0r = tid >> 6;              // staging row 0..7 (+8 for v1)
    const int f0c = (tid & 63) << 2;       // bf16 col within row

    // prologue: global loads for iter 0
    float4 v0, v1;
    {
        const size_t base = ((size_t)(tc * 16) * 64 + bq * 16) * 64;
        v0 = xt[base + tid];
        v1 = xt[base + tid + 512];
    }

    #pragma unroll 1
    for (int i = 0; i < 16; i++) {
        const int buf = i & 1;
        // convert + stage current tile
        ushort4 s0, s1;
        s0.x = f2bf(v0.x); s0.y = f2bf(v0.y); s0.z = f2bf(v0.z); s0.w = f2bf(v0.w);
        s1.x = f2bf(v1.x); s1.y = f2bf(v1.y); s1.z = f2bf(v1.z); s1.w = f2bf(v1.w);
        *reinterpret_cast<ushort4*>(&xsb[buf][f0r * LDXB + f0c]) = s0;
        *reinterpret_cast<ushort4*>(&xsb[buf][(f0r + 8) * LDXB + f0c]) = s1;
        // issue next tile's global loads (in flight during compute)
        if (i < 15) {
            const size_t base = ((size_t)(tc * 16 + i + 1) * 64 + bq * 16) * 64;
            v0 = xt[base + tid];
            v1 = xt[base + tid + 512];
        }
        __syncthreads();

        // ---- GEMM: 3 gates x 8 ksteps, B frag shared across gates
        floatx4 acc0 = {0.f,0.f,0.f,0.f}, acc1 = {0.f,0.f,0.f,0.f}, acc2 = {0.f,0.f,0.f,0.f};
        const unsigned short* xb = xsb[buf];
        #pragma unroll
        for (int ks = 0; ks < 8; ks++) {
            const bf16x8 bfrag = *reinterpret_cast<const bf16x8*>(
                &xb[lr * LDXB + ks * 32 + lq * 8]);
            acc0 = __builtin_amdgcn_mfma_f32_16x16x32_bf16(afrag[0][ks], bfrag, acc0, 0, 0, 0);
            acc1 = __builtin_amdgcn_mfma_f32_16x16x32_bf16(afrag[1][ks], bfrag, acc1, 0, 0, 0);
            acc2 = __builtin_amdgcn_mfma_f32_16x16x32_bf16(afrag[2][ks], bfrag, acc2, 0, 0, 0);
        }

        // ---- GRU epilogue in registers: lane = (m_local=lr), h = hbase+lq*4+reg
        float o[4];
        #pragma unroll
        for (int reg = 0; reg < 4; reg++) {
            const float r = sigf(acc0[reg] + gp[reg].x);
            const float z = sigf(acc1[reg] + gp[reg].y);
            const float e = __expf(-2.0f * (acc2[reg] + bn[reg] + r * gp[reg].z));
            const float n = (1.0f - e) / (1.0f + e);
            o[reg] = (1.0f - z) * n + z * gp[reg].w;
        }

        // ---- transpose via per-wave LDS tile, then coalesced 64B stores
        *reinterpret_cast<float4*>(&epi[wid][lr * 20 + lq * 4]) =
            make_float4(o[0], o[1], o[2], o[3]);
        const int m2 = lane >> 2, hs = lane & 3;
        const float4 ov = *reinterpret_cast<const float4*>(
            &epi[wid][m2 * 20 + hs * 4]);

        const int t  = tc * 16 + i;
        const int m0 = t * 64 + bq * 16;
        *reinterpret_cast<float4*>(out + (size_t)(m0 + m2) * H_DIM + hbase + hs * 4) = ov;
        if (t == T_DIM - 1)
            *reinterpret_cast<float4*>(out + OUT_MAIN +
                (size_t)(bq * 16 + m2) * H_DIM + hbase + hs * 4) = ov;
    }
}

extern "C" void kernel_launch(void* const* d_in, const int* in_sizes, int n_in,
                              void* d_out, int out_size, void* d_ws, size_t ws_size,
                              hipStream_t stream) {
    const float* x    = (const float*)d_in[0];
    const float* hid  = (const float*)d_in[1];
    const float* w_ih = (const float*)d_in[2];
    const float* w_hh = (const float*)d_in[3];
    const float* b_ih = (const float*)d_in[4];
    const float* b_hh = (const float*)d_in[5];
    float* out = (float*)d_out;

    char* ws = (char*)d_ws;
    unsigned short* wsA = (unsigned short*)ws;              // 393216 B
    float4* ghpack = (float4*)(ws + 393216);                // 262144 B
    float*  biasn  = (float*)(ws + 393216 + 262144);        // 1024 B

    gru_prep<<<161, 256, 0, stream>>>(hid, w_ih, w_hh, b_ih, b_hh, wsA, ghpack, biasn);
    gru_main<<<1024, 512, 0, stream>>>(x, wsA, ghpack, biasn, out);
}